// Round 12
// baseline (1199.686 us; speedup 1.0000x reference)
//
#include <hip/hip_runtime.h>

#define CUBE 32

__device__ __forceinline__ float sgpr_f(float v) {
    int i = __builtin_amdgcn_readfirstlane(__float_as_int(v));
    return __int_as_float(i);
}

// ---------------- Kernel A: surface = x @ W_in^T + b_in ----------------
__global__ __launch_bounds__(256) void in_gemm(
    const float* __restrict__ x,
    const float* __restrict__ W_in,
    const float* __restrict__ b_in,
    float* __restrict__ surface)
{
    __shared__ __align__(16) float As[16][68];
    __shared__ __align__(16) float Bs[16][68];
    const int t  = threadIdx.x;
    const int tx = t & 15, ty = t >> 4;
    const int bn = blockIdx.x * 64;
    const int bb = blockIdx.y * 64;

    float acc[4][4];
#pragma unroll
    for (int i = 0; i < 4; ++i)
#pragma unroll
        for (int j = 0; j < 4; ++j) acc[i][j] = 0.0f;

    for (int k0 = 0; k0 < 784; k0 += 16) {
        const int e  = t * 4;
        const int r  = e >> 4;
        const int kk = e & 15;
        float4 av = *(const float4*)&x[(size_t)(bb + r) * 784 + k0 + kk];
        float4 bv = *(const float4*)&W_in[(size_t)(bn + r) * 784 + k0 + kk];
        As[kk + 0][r] = av.x; As[kk + 1][r] = av.y; As[kk + 2][r] = av.z; As[kk + 3][r] = av.w;
        Bs[kk + 0][r] = bv.x; Bs[kk + 1][r] = bv.y; Bs[kk + 2][r] = bv.z; Bs[kk + 3][r] = bv.w;
        __syncthreads();
#pragma unroll
        for (int kki = 0; kki < 16; ++kki) {
            float4 a = *(const float4*)&As[kki][ty * 4];
            float4 b = *(const float4*)&Bs[kki][tx * 4];
            float aa[4] = {a.x, a.y, a.z, a.w};
            float bbv[4] = {b.x, b.y, b.z, b.w};
#pragma unroll
            for (int i = 0; i < 4; ++i)
#pragma unroll
                for (int j = 0; j < 4; ++j)
                    acc[i][j] = fmaf(aa[i], bbv[j], acc[i][j]);
        }
        __syncthreads();
    }
#pragma unroll
    for (int i = 0; i < 4; ++i) {
        const int row = bb + ty * 4 + i;
#pragma unroll
        for (int j = 0; j < 4; ++j) {
            const int col = bn + tx * 4 + j;
            surface[(size_t)row * 1024 + col] = acc[i][j] + b_in[col];
        }
    }
}

// ---------------- Kernel B: cube evolution + output GEMM -----------------
// r11 structure (512 thr, 2 voxels/thread, f32 LDS S[32][34][34], in-place
// 4-deep write pipeline, barrier every 4 phases) + ONE change: the 6 float2
// window reads are software-pipelined ONE PLANE AHEAD (w/v ping-pong).
// Phase p issues plane p+1's reads, computes on plane p's registers loaded
// in phase p-1 -> ds_read latency hides under the 54 FMAs.
// Race-check: plane p+1 is written at phase p+5 (delay-4 pipeline); p -> p+5
// always crosses >=1 barrier (every-4 epochs), so the early read is safe.

#define REP32(M) M(0)M(1)M(2)M(3)M(4)M(5)M(6)M(7)M(8)M(9)M(10)M(11)M(12)M(13)M(14)M(15)M(16)M(17)M(18)M(19)M(20)M(21)M(22)M(23)M(24)M(25)M(26)M(27)M(28)M(29)M(30)M(31)

#define LOADW(R, pp)                                                           \
    R##A0 = *(const float2*)&S[pp][ty + 0][tx2];                               \
    R##B0 = *(const float2*)&S[pp][ty + 0][tx2 + 2];                           \
    R##A1 = *(const float2*)&S[pp][ty + 1][tx2];                               \
    R##B1 = *(const float2*)&S[pp][ty + 1][tx2 + 2];                           \
    R##A2 = *(const float2*)&S[pp][ty + 2][tx2];                               \
    R##B2 = *(const float2*)&S[pp][ty + 2][tx2 + 2];

// out0 (x=2tx): l,c,r = A.x,A.y,B.x ; out1 (x=2tx+1): A.y,B.x,B.y
#define ROW3(v0a, v1a, wl, wc, wr, A, B)                                       \
    v0a = fmaf(wl, A.x, v0a); v0a = fmaf(wc, A.y, v0a); v0a = fmaf(wr, B.x, v0a); \
    v1a = fmaf(wl, A.y, v1a); v1a = fmaf(wc, B.x, v1a); v1a = fmaf(wr, B.y, v1a);

// Phase p: barrier every 4; prefetch plane p+1 -> NXT regs; write plane p-4
// from pend; FMA on CUR regs (plane p, loaded in phase p-1); finalize out p-1
// into pend slot (p+2)%3.
#define PLANE(p, q, w4, CUR, NXT, aN0, aN1, aC0, aC1, aP0, aP1, PD0, PD1) {    \
    if ((p) % 4 == 0) __syncthreads();                                         \
    nb_##p = *(const float2*)&nbias[(p) * 1024 + nboff];                       \
    if ((p) < 31) { LOADW(NXT, (p) + 1) }                                      \
    if ((p) >= 4) {                                                            \
        S[w4][ty + 1][tx2 + 1] = PD0;                                          \
        S[w4][ty + 1][tx2 + 2] = PD1;                                          \
    }                                                                          \
    if ((p) < 31) {                                                            \
        ROW3(aN0, aN1, cw0, cw1, cw2, CUR##A0, CUR##B0)                        \
        ROW3(aN0, aN1, cw3, cw4, cw5, CUR##A1, CUR##B1)                        \
        ROW3(aN0, aN1, cw6, cw7, cw8, CUR##A2, CUR##B2)                        \
    }                                                                          \
    ROW3(aC0, aC1, cw9,  cw10, cw11, CUR##A0, CUR##B0)                         \
    ROW3(aC0, aC1, cw12, cw13, cw14, CUR##A1, CUR##B1)                         \
    ROW3(aC0, aC1, cw15, cw16, cw17, CUR##A2, CUR##B2)                         \
    if ((p) >= 1) {                                                            \
        ROW3(aP0, aP1, cw18, cw19, cw20, CUR##A0, CUR##B0)                     \
        ROW3(aP0, aP1, cw21, cw22, cw23, CUR##A1, CUR##B1)                     \
        ROW3(aP0, aP1, cw24, cw25, cw26, CUR##A2, CUR##B2)                     \
        const float pre0 = aP0 + nb_##q.x + (((q) == 0) ? sf0 : 0.0f);         \
        const float pre1 = aP1 + nb_##q.y + (((q) == 0) ? sf1 : 0.0f);         \
        const float h0 = 1.0f - 2.0f * __builtin_amdgcn_rcpf(                  \
            __builtin_amdgcn_exp2f(pre0 * 2.8853900817779268f) + 1.0f);        \
        const float h1 = 1.0f - 2.0f * __builtin_amdgcn_rcpf(                  \
            __builtin_amdgcn_exp2f(pre1 * 2.8853900817779268f) + 1.0f);        \
        PD0 = 0.5f * (cc0 + h0);                                               \
        PD1 = 0.5f * (cc1 + h1);                                               \
        aP0 = 0.0f; aP1 = 0.0f;                                                \
    }                                                                          \
    cc0 = CUR##A1.y; cc1 = CUR##B1.x;                                          \
}

__global__ __launch_bounds__(512) void cube_evolve(
    const float* __restrict__ surface,   // [1024][1024]
    const float* __restrict__ conv_w,    // [27]  (kd,ky,kx)
    const float* __restrict__ nbias,     // [32768] (d,y,x)
    const float* __restrict__ W_out,     // [10][32768]
    const float* __restrict__ b_out,     // [10]
    const int*   __restrict__ steps_p,   // [1]
    float* __restrict__ out)             // [1024][10]
{
    __shared__ float S[32][34][34];      // 147,968 B; halo rows/cols stay 0
    __shared__ float red[10][8];

    const int b   = blockIdx.x;
    const int tx  = threadIdx.x;         // 0..15, owns x = 2tx, 2tx+1
    const int ty  = threadIdx.y;         // 0..31
    const int tid = ty * 16 + tx;
    const int tx2 = tx * 2;              // halo-coord base of the 4-wide window
    const int nboff = ty * 32 + tx2;
    const int steps = steps_p[0];

    // zero state + halos
    for (int i = tid; i < 32 * 34 * 34; i += 512) ((float*)S)[i] = 0.0f;

    // conv weights -> uniform scalars (SGPRs)
    const float cw0  = sgpr_f(conv_w[0]),  cw1  = sgpr_f(conv_w[1]),  cw2  = sgpr_f(conv_w[2]);
    const float cw3  = sgpr_f(conv_w[3]),  cw4  = sgpr_f(conv_w[4]),  cw5  = sgpr_f(conv_w[5]);
    const float cw6  = sgpr_f(conv_w[6]),  cw7  = sgpr_f(conv_w[7]),  cw8  = sgpr_f(conv_w[8]);
    const float cw9  = sgpr_f(conv_w[9]),  cw10 = sgpr_f(conv_w[10]), cw11 = sgpr_f(conv_w[11]);
    const float cw12 = sgpr_f(conv_w[12]), cw13 = sgpr_f(conv_w[13]), cw14 = sgpr_f(conv_w[14]);
    const float cw15 = sgpr_f(conv_w[15]), cw16 = sgpr_f(conv_w[16]), cw17 = sgpr_f(conv_w[17]);
    const float cw18 = sgpr_f(conv_w[18]), cw19 = sgpr_f(conv_w[19]), cw20 = sgpr_f(conv_w[20]);
    const float cw21 = sgpr_f(conv_w[21]), cw22 = sgpr_f(conv_w[22]), cw23 = sgpr_f(conv_w[23]);
    const float cw24 = sgpr_f(conv_w[24]), cw25 = sgpr_f(conv_w[25]), cw26 = sgpr_f(conv_w[26]);

    const float2 sfv = *(const float2*)&surface[(size_t)b * 1024 + nboff];
    const float sf0 = sfv.x, sf1 = sfv.y;

    // ping-pong window registers (w = even planes' CUR, v = odd planes' CUR)
    float2 wA0, wB0, wA1, wB1, wA2, wB2;
    float2 vA0, vB0, vA1, vB1, vA2, vB2;

    __syncthreads();
    LOADW(w, 0)                          // prologue: plane 0 (zeros)

    for (int st = 0; st < steps; ++st) {
#define DECL_NB(d) float2 nb_##d;
        REP32(DECL_NB)
#undef DECL_NB
        float a00 = 0.f, a01 = 0.f, a10 = 0.f, a11 = 0.f, a20 = 0.f, a21 = 0.f;
        float pd00, pd01, pd10, pd11, pd20, pd21;   // pend slots 0,1,2 × 2 vox
        float cc0 = 0.f, cc1 = 0.f;
        // (aN, aC, aP) = slots ((p+1)%3, p%3, (p+2)%3); PD = slot (p+2)%3
        PLANE( 0,  0,  0, w, v, a10,a11, a00,a01, a20,a21, pd20,pd21)
        PLANE( 1,  0,  0, v, w, a20,a21, a10,a11, a00,a01, pd00,pd01)
        PLANE( 2,  1,  0, w, v, a00,a01, a20,a21, a10,a11, pd10,pd11)
        PLANE( 3,  2,  0, v, w, a10,a11, a00,a01, a20,a21, pd20,pd21)
        PLANE( 4,  3,  0, w, v, a20,a21, a10,a11, a00,a01, pd00,pd01)
        PLANE( 5,  4,  1, v, w, a00,a01, a20,a21, a10,a11, pd10,pd11)
        PLANE( 6,  5,  2, w, v, a10,a11, a00,a01, a20,a21, pd20,pd21)
        PLANE( 7,  6,  3, v, w, a20,a21, a10,a11, a00,a01, pd00,pd01)
        PLANE( 8,  7,  4, w, v, a00,a01, a20,a21, a10,a11, pd10,pd11)
        PLANE( 9,  8,  5, v, w, a10,a11, a00,a01, a20,a21, pd20,pd21)
        PLANE(10,  9,  6, w, v, a20,a21, a10,a11, a00,a01, pd00,pd01)
        PLANE(11, 10,  7, v, w, a00,a01, a20,a21, a10,a11, pd10,pd11)
        PLANE(12, 11,  8, w, v, a10,a11, a00,a01, a20,a21, pd20,pd21)
        PLANE(13, 12,  9, v, w, a20,a21, a10,a11, a00,a01, pd00,pd01)
        PLANE(14, 13, 10, w, v, a00,a01, a20,a21, a10,a11, pd10,pd11)
        PLANE(15, 14, 11, v, w, a10,a11, a00,a01, a20,a21, pd20,pd21)
        PLANE(16, 15, 12, w, v, a20,a21, a10,a11, a00,a01, pd00,pd01)
        PLANE(17, 16, 13, v, w, a00,a01, a20,a21, a10,a11, pd10,pd11)
        PLANE(18, 17, 14, w, v, a10,a11, a00,a01, a20,a21, pd20,pd21)
        PLANE(19, 18, 15, v, w, a20,a21, a10,a11, a00,a01, pd00,pd01)
        PLANE(20, 19, 16, w, v, a00,a01, a20,a21, a10,a11, pd10,pd11)
        PLANE(21, 20, 17, v, w, a10,a11, a00,a01, a20,a21, pd20,pd21)
        PLANE(22, 21, 18, w, v, a20,a21, a10,a11, a00,a01, pd00,pd01)
        PLANE(23, 22, 19, v, w, a00,a01, a20,a21, a10,a11, pd10,pd11)
        PLANE(24, 23, 20, w, v, a10,a11, a00,a01, a20,a21, pd20,pd21)
        PLANE(25, 24, 21, v, w, a20,a21, a10,a11, a00,a01, pd00,pd01)
        PLANE(26, 25, 22, w, v, a00,a01, a20,a21, a10,a11, pd10,pd11)
        PLANE(27, 26, 23, v, w, a10,a11, a00,a01, a20,a21, pd20,pd21)
        PLANE(28, 27, 24, w, v, a20,a21, a10,a11, a00,a01, pd00,pd01)
        PLANE(29, 28, 25, v, w, a00,a01, a20,a21, a10,a11, pd10,pd11)
        PLANE(30, 29, 26, w, v, a10,a11, a00,a01, a20,a21, pd20,pd21)
        PLANE(31, 30, 27, v, w, a20,a21, a10,a11, a00,a01, pd00,pd01)
        { // tail: finalize output 31 (aC of phase 31 = slot1), flush pending
          // planes 28(pd1), 29(pd2), 30(pd0), 31; prefetch next step's plane 0.
            const float pre0 = a10 + nb_31.x;
            const float pre1 = a11 + nb_31.y;
            const float h0 = 1.0f - 2.0f * __builtin_amdgcn_rcpf(
                __builtin_amdgcn_exp2f(pre0 * 2.8853900817779268f) + 1.0f);
            const float h1 = 1.0f - 2.0f * __builtin_amdgcn_rcpf(
                __builtin_amdgcn_exp2f(pre1 * 2.8853900817779268f) + 1.0f);
            const float v310 = 0.5f * (cc0 + h0);
            const float v311 = 0.5f * (cc1 + h1);
            __syncthreads();   // waves may still be reading planes 28..31
            S[28][ty + 1][tx2 + 1] = pd10; S[28][ty + 1][tx2 + 2] = pd11;
            S[29][ty + 1][tx2 + 1] = pd20; S[29][ty + 1][tx2 + 2] = pd21;
            S[30][ty + 1][tx2 + 1] = pd00; S[30][ty + 1][tx2 + 2] = pd01;
            S[31][ty + 1][tx2 + 1] = v310; S[31][ty + 1][tx2 + 2] = v311;
            LOADW(w, 0)        // plane 0 (updated at phase 4): no alias w/ 28-31
        }
    }
    __syncthreads();   // state complete & visible

    // ---- fused output GEMM: out[b][o] = sum_flat s * W_out[o][flat] + b_out[o]
    float p0 = 0.f, p1 = 0.f, p2 = 0.f, p3 = 0.f, p4 = 0.f;
    float p5 = 0.f, p6 = 0.f, p7 = 0.f, p8 = 0.f, p9 = 0.f;
    const int base = tid * 4;
#pragma unroll 4
    for (int j = 0; j < 16; ++j) {
        const int idx = base + j * 2048;
        const int d   = idx >> 10;
        const int rem = idx & 1023;
        const int yy  = rem >> 5;
        const int xx  = rem & 31;
        const float s0v = S[d][yy + 1][xx + 1];
        const float s1v = S[d][yy + 1][xx + 2];
        const float s2v = S[d][yy + 1][xx + 3];
        const float s3v = S[d][yy + 1][xx + 4];
#define OACC(o) { const float4 wv = *(const float4*)&W_out[(size_t)(o) * 32768 + idx]; \
        p##o = fmaf(s0v, wv.x, p##o); p##o = fmaf(s1v, wv.y, p##o);            \
        p##o = fmaf(s2v, wv.z, p##o); p##o = fmaf(s3v, wv.w, p##o); }
        OACC(0) OACC(1) OACC(2) OACC(3) OACC(4)
        OACC(5) OACC(6) OACC(7) OACC(8) OACC(9)
#undef OACC
    }

    const int lane = tid & 63, wvi = tid >> 6;
#define RED(o) { float t = p##o;                                               \
    t += __shfl_down(t, 32, 64); t += __shfl_down(t, 16, 64);                  \
    t += __shfl_down(t, 8, 64);  t += __shfl_down(t, 4, 64);                   \
    t += __shfl_down(t, 2, 64);  t += __shfl_down(t, 1, 64);                   \
    if (lane == 0) red[o][wvi] = t; }
    RED(0) RED(1) RED(2) RED(3) RED(4) RED(5) RED(6) RED(7) RED(8) RED(9)
#undef RED
    __syncthreads();
    if (tid < 10) {
        float sum = b_out[tid];
#pragma unroll
        for (int w8 = 0; w8 < 8; ++w8) sum += red[tid][w8];
        out[(size_t)b * 10 + tid] = sum;
    }
}

// ---------------- launcher ----------------
extern "C" void kernel_launch(void* const* d_in, const int* in_sizes, int n_in,
                              void* d_out, int out_size, void* d_ws, size_t ws_size,
                              hipStream_t stream) {
    const float* x      = (const float*)d_in[0];
    const float* W_in   = (const float*)d_in[1];
    const float* b_in   = (const float*)d_in[2];
    const float* conv_w = (const float*)d_in[3];
    const float* nbias  = (const float*)d_in[4];
    const float* W_out  = (const float*)d_in[5];
    const float* b_out  = (const float*)d_in[6];
    const int*   steps  = (const int*)d_in[7];
    float* out = (float*)d_out;
    float* surface = (float*)d_ws;   // 1024*1024 f32 = 4 MB scratch

    in_gemm<<<dim3(16, 16), 256, 0, stream>>>(x, W_in, b_in, surface);
    cube_evolve<<<1024, dim3(16, 32), 0, stream>>>(surface, conv_w, nbias,
                                                   W_out, b_out, steps, out);
}